// Round 10
// baseline (59.836 us; speedup 1.0000x reference)
//
#include <hip/hip_runtime.h>

#define N_NEURONS 100000
#define MAX_DELAY 5
#define NSYN 5
#define T_STEPS 20
#define N_LGN 17400
#define N_BKG 100
#define N_SRC (N_LGN + N_BKG)        // 17500
#define E_REC 2000000
#define E_LGN 600000
#define E_BKG 200000
#define E_EXT (E_LGN + E_BKG)        // 800000
#define DT 1.0f
#define NN_PER_BLK 64
#define NTGT 1563                    // consumer blocks = ceil(N/64)
#define DIRW (NTGT + 1)              // 1564
#define NCHUNK 256                   // producer chunks
#define CHUNK 3125                   // NCHUNK*CHUNK == E_EXT exactly
#define RUNW (CHUNK * 8)             // ints per chunk run region (sized for ALL edges firing)
#define ACC_STRIDE 101               // 100 + 1 pad
#define SCALE_F 16777216.0f          // 2^24 fixed-point (order-invariant accumulation)
#define INV_SCALE (1.0 / 16777216.0)

// ---------------- ws layout (4-byte units) ----------------
#define OFF_FLAG   0u                // int[32]: [0]=any-spike flag
#define OFF_BITS   32u               // uint[N_SRC]
#define OFF_DIR    17536u            // int[NCHUNK][DIRW] = 400,384 (exclusive scans + total)
#define OFF_RUNS   417920u           // int[NCHUNK][CHUNK][8] = 6,400,000 (32B-aligned records)
#define OFF_ZBUF   6817920u          // float[5N]  (fallback only)
#define OFF_V      7317920u
#define OFF_R      7417920u
#define OFF_ASC    7517920u          // float[2N]
#define OFF_PR     7717920u          // float[5N]
#define OFF_PC     8217920u          // float[5N]
#define OFF_INPI   8717920u          // int[5N]
// ends 9,217,920 units = 36.9 MB (harness poison shows ws = 256 MiB)

// Zero flag + build 20-bit spike masks.
__global__ void prep(const float* __restrict__ lgn, const float* __restrict__ bkg,
                     unsigned* __restrict__ bits, int* __restrict__ zp) {
    int tid = blockIdx.x * blockDim.x + threadIdx.x;
    if (tid < 32) zp[tid] = 0;
    int i = tid - 32;
    if (i < 0 || i >= N_SRC) return;
    unsigned b = 0;
    if (i < N_LGN) {
#pragma unroll
        for (int t = 0; t < T_STEPS; ++t)
            if (lgn[t * N_LGN + i] != 0.0f) b |= (1u << t);
    } else {
        int j = i - N_LGN;
#pragma unroll
        for (int t = 0; t < T_STEPS; ++t)
            if (bkg[t * N_BKG + j] != 0.0f) b |= (1u << t);
    }
    bits[i] = b;
}

// Counting-sort pack: ZERO global atomics. Each block owns 3125 edges:
// LDS histogram over 1563 consumer targets -> LDS exclusive scan -> directory
// row (coalesced) -> re-walk edges writing quantized 32B records into the
// chunk's PRIVATE dense run region (L2-windowed, write-back coalesced).
// Slot order within a (chunk,target) group varies across replays (LDS cursor),
// but consumer int accumulation is order-invariant -> deterministic output.
__global__ void __launch_bounds__(256) sort_pack(
    const int* __restrict__ lgn_idx, const float* __restrict__ lgn_w,
    const float* __restrict__ lgn_fac,
    const int* __restrict__ bkg_idx, const float* __restrict__ bkg_w,
    const float* __restrict__ bkg_fac,
    const unsigned* __restrict__ bits,
    int* __restrict__ dir, int* __restrict__ runs)
{
    __shared__ int hist[NTGT];
    __shared__ int cur[NTGT];
    __shared__ int part[256];
    int tid = threadIdx.x, c = blockIdx.x;
    int e0 = c * CHUNK, e1 = e0 + CHUNK;

    for (int i = tid; i < NTGT; i += 256) hist[i] = 0;
    __syncthreads();

    // Phase A: histogram of firing edges by target block.
    for (int e = e0 + tid; e < e1; e += 256) {
        int post, srow;
        if (e < E_LGN) { int2 p = ((const int2*)lgn_idx)[e]; post = p.x; srow = p.y; }
        else           { int2 p = ((const int2*)bkg_idx)[e - E_LGN]; post = p.x; srow = N_LGN + p.y; }
        if (bits[srow]) atomicAdd(&hist[post >> 6], 1);
    }
    __syncthreads();

    // Exclusive scan over 1563 entries: 7-wide serial per thread + block scan.
    int base = tid * 7;
    int loc[7]; int s = 0;
#pragma unroll
    for (int j = 0; j < 7; ++j) {
        int ix = base + j;
        int v = (ix < NTGT) ? hist[ix] : 0;
        loc[j] = s; s += v;
    }
    part[tid] = s;
    __syncthreads();
    for (int off = 1; off < 256; off <<= 1) {
        int v = (tid >= off) ? part[tid - off] : 0;
        __syncthreads();
        part[tid] += v;
        __syncthreads();
    }
    int excl = part[tid] - s;
#pragma unroll
    for (int j = 0; j < 7; ++j) {
        int ix = base + j;
        if (ix < NTGT) {
            int ex = excl + loc[j];
            cur[ix] = ex;
            dir[(size_t)c * DIRW + ix] = ex;
        }
    }
    if (tid == 255) dir[(size_t)c * DIRW + NTGT] = part[255];   // total
    __syncthreads();

    // Phase B: write records at LDS-cursor slots (dense private region).
    int* run = runs + (size_t)c * RUNW;
    for (int e = e0 + tid; e < e1; e += 256) {
        int post, srow; float w; const float* f;
        if (e < E_LGN) {
            int2 p = ((const int2*)lgn_idx)[e]; post = p.x; srow = p.y;
            w = lgn_w[e]; f = lgn_fac + 5 * (size_t)e;
        } else {
            int b = e - E_LGN;
            int2 p = ((const int2*)bkg_idx)[b]; post = p.x; srow = N_LGN + p.y;
            w = bkg_w[b]; f = bkg_fac + 5 * (size_t)b;
        }
        unsigned m = bits[srow];
        if (!m) continue;
        float wsc = w * SCALE_F;
        int q0 = __float2int_rn(wsc * f[0]);
        int q1 = __float2int_rn(wsc * f[1]);
        int q2 = __float2int_rn(wsc * f[2]);
        int q3 = __float2int_rn(wsc * f[3]);
        int q4 = __float2int_rn(wsc * f[4]);
        int slot = atomicAdd(&cur[post >> 6], 1);               // LDS atomic
        int4* d = (int4*)(run + (size_t)slot * 8);
        d[0] = make_int4((int)m, q0, q1, q2);
        d[1] = make_int4(q3, q4, post & 63, 0);
    }
}

// Consumer: thread t streams chunk t's group for this block (dir-indexed,
// pure loads), LDS-atomics into acc[post_local]; then 64 threads run the
// 20-step GLIF scan (numerics identical to round 9's passing kernel).
__global__ void __launch_bounds__(256) fused_scan(
    const int* __restrict__ dir, const int* __restrict__ runs,
    const float* __restrict__ decay, const float* __restrict__ cf,
    const float* __restrict__ vres, const float* __restrict__ tref,
    const float* __restrict__ kk, const float* __restrict__ aamps,
    const float* __restrict__ vth, const float* __restrict__ norm,
    const float* __restrict__ gg, const float* __restrict__ sdec,
    const float* __restrict__ psci,
    float* __restrict__ out, int* __restrict__ flag)
{
    __shared__ int accs[NN_PER_BLK * ACC_STRIDE];
    int tid = threadIdx.x;
    int b = blockIdx.x;
    int n0 = b * NN_PER_BLK;

    for (int i = tid; i < NN_PER_BLK * ACC_STRIDE; i += 256) accs[i] = 0;
    __syncthreads();

    {
        const int* dp = dir + (size_t)tid * DIRW + b;
        int d0 = dp[0], d1 = dp[1];
        const int* run = runs + (size_t)tid * RUNW;
        for (int k = d0; k < d1; ++k) {
            int4 a  = *(const int4*)(run + (size_t)k * 8);
            int4 bb = *(const int4*)(run + (size_t)k * 8 + 4);
            unsigned m = (unsigned)a.x;
            int* acc = &accs[bb.z * ACC_STRIDE];
            while (m) {
                int t = __ffs(m) - 1;
                m &= m - 1;
                atomicAdd(&acc[t * 5 + 0], a.y);
                atomicAdd(&acc[t * 5 + 1], a.z);
                atomicAdd(&acc[t * 5 + 2], a.w);
                atomicAdd(&acc[t * 5 + 3], bb.x);
                atomicAdd(&acc[t * 5 + 4], bb.y);
            }
        }
    }
    __syncthreads();

    if (tid >= NN_PER_BLK) return;
    int n = n0 + tid;
    if (n >= N_NEURONS) return;
    const int* acc = &accs[tid * ACC_STRIDE];

    float dec = decay[n], cfa = cf[n], vr = vres[n], tr = tref[n];
    float ek0 = expf(-DT * kk[2 * n]), ek1 = expf(-DT * kk[2 * n + 1]);
    float aa0 = aamps[2 * n], aa1 = aamps[2 * n + 1];
    float vt = vth[n], nm = norm[n], g = gg[n];
    float sd0 = sdec[0], sd1 = sdec[1], sd2 = sdec[2], sd3 = sdec[3], sd4 = sdec[4];
    float pi0 = psci[0], pi1 = psci[1], pi2 = psci[2], pi3 = psci[3], pi4 = psci[4];

    float pr0 = 0.f, pr1 = 0.f, pr2 = 0.f, pr3 = 0.f, pr4 = 0.f;
    float pc0 = 0.f, pc1 = 0.f, pc2 = 0.f, pc3 = 0.f, pc4 = 0.f;
    float v = 0.f, r = 0.f, a0 = 0.f, a1 = 0.f, pz = 0.f;
    bool anyf = false;

#pragma unroll
    for (int t = 0; t < T_STEPS; ++t) {
        float ic = pc0 + pc1 + pc2 + pc3 + pc4;      // input_current uses OLD psc
        float c1 = ic + a0 + a1 + g;
        float dv = dec * v + cfa * c1;
        float nv = (pz > 0.5f) ? vr : dv;
        float nr = r + pz * tr - DT;
        nr = fminf(fmaxf(nr, 0.0f), tr);
        a0 = ek0 * a0 + pz * aa0;
        a1 = ek1 * a1 + pz * aa1;

        float i0 = (float)((double)acc[t * 5 + 0] * INV_SCALE);
        float i1 = (float)((double)acc[t * 5 + 1] * INV_SCALE);
        float i2 = (float)((double)acc[t * 5 + 2] * INV_SCALE);
        float i3 = (float)((double)acc[t * 5 + 3] * INV_SCALE);
        float i4 = (float)((double)acc[t * 5 + 4] * INV_SCALE);

        float np0 = pc0 * sd0 + DT * sd0 * pr0;      // new psc from OLD psc_rise
        float np1 = pc1 * sd1 + DT * sd1 * pr1;
        float np2 = pc2 * sd2 + DT * sd2 * pr2;
        float np3 = pc3 * sd3 + DT * sd3 * pr3;
        float np4 = pc4 * sd4 + DT * sd4 * pr4;
        pr0 = pr0 * sd0 + i0 * pi0;  pc0 = np0;
        pr1 = pr1 * sd1 + i1 * pi1;  pc1 = np1;
        pr2 = pr2 * sd2 + i2 * pi2;  pc2 = np2;
        pr3 = pr3 * sd3 + i3 * pi3;  pc3 = np3;
        pr4 = pr4 * sd4 + i4 * pi4;  pc4 = np4;

        v = nv; r = nr;
        float vsc = (nv - vt) / nm;
        float z = (vsc > 0.0f) ? 1.0f : 0.0f;
        float nz = (nr > 0.0f) ? 0.0f : z;
        out[(size_t)t * N_NEURONS + n] = nz;
        pz = nz;
        anyf = anyf || (nz != 0.0f);
    }
    if (anyf) atomicAdd(flag, 1);
}

// Exact coupled redo inside ONE workgroup; early-exits if no spike detected.
__global__ void __launch_bounds__(1024) fallback_redo(
    const int* __restrict__ dir, const int* __restrict__ runs,
    const int* __restrict__ rec_idx, const float* __restrict__ rec_w,
    const float* __restrict__ rec_fac,
    const float* __restrict__ decay, const float* __restrict__ cf,
    const float* __restrict__ vres, const float* __restrict__ tref,
    const float* __restrict__ kk, const float* __restrict__ aamps,
    const float* __restrict__ vth, const float* __restrict__ norm,
    const float* __restrict__ gg, const float* __restrict__ sdec,
    const float* __restrict__ psci,
    float* __restrict__ zbuf, float* __restrict__ vv, float* __restrict__ rr,
    float* __restrict__ asc, float* __restrict__ pra, float* __restrict__ pca,
    int* __restrict__ inpi, float* __restrict__ out, const int* __restrict__ flag)
{
    if (flag[0] == 0) return;
    int tid = threadIdx.x;
    for (int i = tid; i < N_NEURONS; i += 1024) { vv[i] = 0.f; rr[i] = 0.f; }
    for (int i = tid; i < 2 * N_NEURONS; i += 1024) asc[i] = 0.f;
    for (int i = tid; i < NSYN * N_NEURONS; i += 1024) { pra[i] = 0.f; pca[i] = 0.f; }
    for (int i = tid; i < MAX_DELAY * N_NEURONS; i += 1024) zbuf[i] = 0.f;
    __syncthreads();

    for (int t = 0; t < T_STEPS; ++t) {
        for (int i = tid; i < NSYN * N_NEURONS; i += 1024) inpi[i] = 0;
        __syncthreads();
        // external input for step t: thread c walks chunk c via its directory
        // (device atomics within the single block; int sums order-invariant)
        if (tid < NCHUNK) {
            const int* dp  = dir + (size_t)tid * DIRW;
            const int* run = runs + (size_t)tid * RUNW;
            for (int b2 = 0; b2 < NTGT; ++b2) {
                int d0 = dp[b2], d1 = dp[b2 + 1];
                for (int k = d0; k < d1; ++k) {
                    int4 a  = *(const int4*)(run + (size_t)k * 8);
                    int4 bb = *(const int4*)(run + (size_t)k * 8 + 4);
                    if (((unsigned)a.x >> t) & 1u) {
                        int post = b2 * NN_PER_BLK + bb.z;
                        atomicAdd(&inpi[post * NSYN + 0], a.y);
                        atomicAdd(&inpi[post * NSYN + 1], a.z);
                        atomicAdd(&inpi[post * NSYN + 2], a.w);
                        atomicAdd(&inpi[post * NSYN + 3], bb.x);
                        atomicAdd(&inpi[post * NSYN + 4], bb.y);
                    }
                }
            }
        }
        __syncthreads();
        if (t > 0) {
            for (int e = tid; e < E_REC; e += 1024) {
                int2 pcol = ((const int2*)rec_idx)[e];
                int post = pcol.x, col = pcol.y;
                int d1 = col / N_NEURONS;
                int pre = col - d1 * N_NEURONS;
                int st = t - 1 - d1;
                if (st < 0) continue;
                if (zbuf[(st % MAX_DELAY) * N_NEURONS + pre] != 0.0f) {
                    float w = rec_w[e];
                    atomicAdd(&inpi[post * NSYN + 0], __float2int_rn(w * rec_fac[5 * e + 0] * SCALE_F));
                    atomicAdd(&inpi[post * NSYN + 1], __float2int_rn(w * rec_fac[5 * e + 1] * SCALE_F));
                    atomicAdd(&inpi[post * NSYN + 2], __float2int_rn(w * rec_fac[5 * e + 2] * SCALE_F));
                    atomicAdd(&inpi[post * NSYN + 3], __float2int_rn(w * rec_fac[5 * e + 3] * SCALE_F));
                    atomicAdd(&inpi[post * NSYN + 4], __float2int_rn(w * rec_fac[5 * e + 4] * SCALE_F));
                }
            }
        }
        __syncthreads();
        for (int n = tid; n < N_NEURONS; n += 1024) {
            float pz = (t == 0) ? 0.f : zbuf[((t - 1) % MAX_DELAY) * N_NEURONS + n];
            float prx[NSYN], pcx[NSYN];
            float ic = 0.f;
#pragma unroll
            for (int s = 0; s < NSYN; ++s) {
                prx[s] = pra[n * NSYN + s];
                pcx[s] = pca[n * NSYN + s];
                ic += pcx[s];
            }
            float a0 = asc[2 * n], a1 = asc[2 * n + 1];
            float c1 = ic + a0 + a1 + gg[n];
            float dv = decay[n] * vv[n] + cf[n] * c1;
            float nv = (pz > 0.5f) ? vres[n] : dv;
            float tr = tref[n];
            float nr = rr[n] + pz * tr - DT;
            nr = fminf(fmaxf(nr, 0.0f), tr);
            asc[2 * n]     = expf(-DT * kk[2 * n])     * a0 + pz * aamps[2 * n];
            asc[2 * n + 1] = expf(-DT * kk[2 * n + 1]) * a1 + pz * aamps[2 * n + 1];
#pragma unroll
            for (int s = 0; s < NSYN; ++s) {
                float is = (float)((double)inpi[n * NSYN + s] * INV_SCALE);
                float sd = sdec[s];
                float np = pcx[s] * sd + DT * sd * prx[s];
                pra[n * NSYN + s] = prx[s] * sd + is * psci[s];
                pca[n * NSYN + s] = np;
            }
            vv[n] = nv; rr[n] = nr;
            float vsc = (nv - vth[n]) / norm[n];
            float z = (vsc > 0.0f) ? 1.0f : 0.0f;
            float nz = (nr > 0.0f) ? 0.0f : z;
            zbuf[(t % MAX_DELAY) * N_NEURONS + n] = nz;
            out[(size_t)t * N_NEURONS + n] = nz;
        }
        __syncthreads();
    }
}

extern "C" void kernel_launch(void* const* d_in, const int* in_sizes, int n_in,
                              void* d_out, int out_size, void* d_ws, size_t ws_size,
                              hipStream_t stream) {
    const float* lgn_spikes  = (const float*)d_in[0];
    const float* bkg_spikes  = (const float*)d_in[1];
    const int*   rec_indices = (const int*)  d_in[2];
    const float* rec_w       = (const float*)d_in[3];
    const float* rec_factors = (const float*)d_in[4];
    const int*   lgn_indices = (const int*)  d_in[5];
    const float* lgn_w       = (const float*)d_in[6];
    const float* lgn_factors = (const float*)d_in[7];
    const int*   bkg_indices = (const int*)  d_in[8];
    const float* bkg_w       = (const float*)d_in[9];
    const float* bkg_factors = (const float*)d_in[10];
    const float* decay       = (const float*)d_in[11];
    const float* current_factor = (const float*)d_in[12];
    const float* v_reset     = (const float*)d_in[13];
    const float* t_ref       = (const float*)d_in[14];
    const float* k           = (const float*)d_in[15];
    const float* asc_amps    = (const float*)d_in[16];
    const float* v_th        = (const float*)d_in[17];
    const float* normalizer  = (const float*)d_in[18];
    const float* gathered_g  = (const float*)d_in[19];
    const float* syn_decay   = (const float*)d_in[20];
    const float* psc_initial = (const float*)d_in[21];

    float* ws = (float*)d_ws;
    int*      flag = (int*)(ws + OFF_FLAG);
    unsigned* bits = (unsigned*)(ws + OFF_BITS);
    int*      dir  = (int*)(ws + OFF_DIR);
    int*      runs = (int*)(ws + OFF_RUNS);
    float*    zbuf = ws + OFF_ZBUF;
    float*    vv   = ws + OFF_V;
    float*    rr   = ws + OFF_R;
    float*    asc  = ws + OFF_ASC;
    float*    pra  = ws + OFF_PR;
    float*    pca  = ws + OFF_PC;
    int*      inpi = (int*)(ws + OFF_INPI);
    float*    out  = (float*)d_out;

    prep<<<(32 + N_SRC + 255) / 256, 256, 0, stream>>>(lgn_spikes, bkg_spikes, bits, flag);
    sort_pack<<<NCHUNK, 256, 0, stream>>>(
        lgn_indices, lgn_w, lgn_factors, bkg_indices, bkg_w, bkg_factors,
        bits, dir, runs);
    fused_scan<<<NTGT, 256, 0, stream>>>(
        dir, runs,
        decay, current_factor, v_reset, t_ref, k, asc_amps,
        v_th, normalizer, gathered_g, syn_decay, psc_initial,
        out, flag);
    fallback_redo<<<1, 1024, 0, stream>>>(
        dir, runs, rec_indices, rec_w, rec_factors,
        decay, current_factor, v_reset, t_ref, k, asc_amps,
        v_th, normalizer, gathered_g, syn_decay, psc_initial,
        zbuf, vv, rr, asc, pra, pca, inpi, out, flag);
}

// Round 11
// 55.265 us; speedup vs baseline: 1.0827x; 1.0827x over previous
//
#include <hip/hip_runtime.h>

#define N_NEURONS 100000
#define MAX_DELAY 5
#define NSYN 5
#define T_STEPS 20
#define N_LGN 17400
#define N_BKG 100
#define N_SRC (N_LGN + N_BKG)        // 17500
#define E_REC 2000000
#define E_LGN 600000
#define E_BKG 200000
#define E_EXT (E_LGN + E_BKG)        // 800000
#define DT 1.0f
#define NN_PER_BLK 64
#define NTGT 1563                    // consumer blocks = ceil(N/64)
#define DIRW (NTGT + 1)              // 1564
#define NCHUNK 512                   // producer chunks (2 blocks/CU -> ~100% occupancy)
#define CHUNK 1563                   // 512*1563 = 800,256 >= E_EXT
#define RUNW (CHUNK * 8)             // ints per chunk run region (sized for ALL edges firing)
#define ACC_STRIDE 101               // 100 + 1 pad
#define SCALE_F 16777216.0f          // 2^24 fixed-point (order-invariant accumulation)
#define INV_SCALE (1.0 / 16777216.0)

// ---------------- ws layout (4-byte units) ----------------
#define OFF_FLAG   0u                // int[32]: [0]=any-spike flag
#define OFF_BITS   32u               // uint[N_SRC]
#define OFF_DIR    17536u            // int[NCHUNK][DIRW] = 800,768
#define OFF_RUNS   818304u           // int[NCHUNK][CHUNK][8] = 6,402,048
#define OFF_ZBUF   7220352u          // float[5N]  (fallback only)
#define OFF_V      7720352u
#define OFF_R      7820352u
#define OFF_ASC    7920352u          // float[2N]
#define OFF_PR     8120352u          // float[5N]
#define OFF_PC     8620352u          // float[5N]
#define OFF_INPI   9120352u          // int[5N]
// ends 9,620,352 units = 38.5 MB

// Zero flag + build 20-bit spike masks.
__global__ void prep(const float* __restrict__ lgn, const float* __restrict__ bkg,
                     unsigned* __restrict__ bits, int* __restrict__ zp) {
    int tid = blockIdx.x * blockDim.x + threadIdx.x;
    if (tid < 32) zp[tid] = 0;
    int i = tid - 32;
    if (i < 0 || i >= N_SRC) return;
    unsigned b = 0;
    if (i < N_LGN) {
#pragma unroll
        for (int t = 0; t < T_STEPS; ++t)
            if (lgn[t * N_LGN + i] != 0.0f) b |= (1u << t);
    } else {
        int j = i - N_LGN;
#pragma unroll
        for (int t = 0; t < T_STEPS; ++t)
            if (bkg[t * N_BKG + j] != 0.0f) b |= (1u << t);
    }
    bits[i] = b;
}

// Counting-sort pack, occupancy-fixed: 512 blocks x 1024 threads (32 waves/CU).
// Zero global atomics. LDS histogram over 1563 targets -> LDS scan -> directory
// row (coalesced) -> records written into the chunk's private dense run region.
// Slot order within a (chunk,target) group varies across replays (LDS cursor),
// but consumer int accumulation is order-invariant -> deterministic output.
__global__ void __launch_bounds__(1024) sort_pack(
    const int* __restrict__ lgn_idx, const float* __restrict__ lgn_w,
    const float* __restrict__ lgn_fac,
    const int* __restrict__ bkg_idx, const float* __restrict__ bkg_w,
    const float* __restrict__ bkg_fac,
    const unsigned* __restrict__ bits,
    int* __restrict__ dir, int* __restrict__ runs)
{
    __shared__ int hist[NTGT];
    __shared__ int cur[NTGT];
    __shared__ int part[1024];
    int tid = threadIdx.x, c = blockIdx.x;
    int e0 = c * CHUNK;
    int e1 = e0 + CHUNK; if (e1 > E_EXT) e1 = E_EXT;

    for (int i = tid; i < NTGT; i += 1024) hist[i] = 0;
    __syncthreads();

    // Phase A: histogram of firing edges by target block (~1.5 edges/thread).
    for (int e = e0 + tid; e < e1; e += 1024) {
        int post, srow;
        if (e < E_LGN) { int2 p = ((const int2*)lgn_idx)[e]; post = p.x; srow = p.y; }
        else           { int2 p = ((const int2*)bkg_idx)[e - E_LGN]; post = p.x; srow = N_LGN + p.y; }
        if (bits[srow]) atomicAdd(&hist[post >> 6], 1);
    }
    __syncthreads();

    // Exclusive scan over 1563 entries: 2 per thread + 1024-wide block scan.
    int base = tid * 2;
    int v0 = (base < NTGT) ? hist[base] : 0;
    int v1 = (base + 1 < NTGT) ? hist[base + 1] : 0;
    int s = v0 + v1;
    part[tid] = s;
    __syncthreads();
    for (int off = 1; off < 1024; off <<= 1) {
        int v = (tid >= off) ? part[tid - off] : 0;
        __syncthreads();
        part[tid] += v;
        __syncthreads();
    }
    int excl = part[tid] - s;
    if (base < NTGT) {
        cur[base] = excl;
        dir[(size_t)c * DIRW + base] = excl;
    }
    if (base + 1 < NTGT) {
        cur[base + 1] = excl + v0;
        dir[(size_t)c * DIRW + base + 1] = excl + v0;
    }
    if (tid == 1023) dir[(size_t)c * DIRW + NTGT] = part[1023];   // total
    __syncthreads();

    // Phase B: write records at LDS-cursor slots (dense private ~50KB region).
    int* run = runs + (size_t)c * RUNW;
    for (int e = e0 + tid; e < e1; e += 1024) {
        int post, srow; float w; const float* f;
        if (e < E_LGN) {
            int2 p = ((const int2*)lgn_idx)[e]; post = p.x; srow = p.y;
            w = lgn_w[e]; f = lgn_fac + 5 * (size_t)e;
        } else {
            int b = e - E_LGN;
            int2 p = ((const int2*)bkg_idx)[b]; post = p.x; srow = N_LGN + p.y;
            w = bkg_w[b]; f = bkg_fac + 5 * (size_t)b;
        }
        unsigned m = bits[srow];
        if (!m) continue;
        float wsc = w * SCALE_F;
        int q0 = __float2int_rn(wsc * f[0]);
        int q1 = __float2int_rn(wsc * f[1]);
        int q2 = __float2int_rn(wsc * f[2]);
        int q3 = __float2int_rn(wsc * f[3]);
        int q4 = __float2int_rn(wsc * f[4]);
        int slot = atomicAdd(&cur[post >> 6], 1);               // LDS atomic
        int4* d = (int4*)(run + (size_t)slot * 8);
        d[0] = make_int4((int)m, q0, q1, q2);
        d[1] = make_int4(q3, q4, post & 63, 0);
    }
}

// Consumer: thread t streams chunks {t, t+256} for this block (dir-indexed,
// pure loads), LDS-atomics into acc[post_local]; then 64 threads run the
// 20-step GLIF scan (numerics identical to round 10's passing kernel).
__global__ void __launch_bounds__(256) fused_scan(
    const int* __restrict__ dir, const int* __restrict__ runs,
    const float* __restrict__ decay, const float* __restrict__ cf,
    const float* __restrict__ vres, const float* __restrict__ tref,
    const float* __restrict__ kk, const float* __restrict__ aamps,
    const float* __restrict__ vth, const float* __restrict__ norm,
    const float* __restrict__ gg, const float* __restrict__ sdec,
    const float* __restrict__ psci,
    float* __restrict__ out, int* __restrict__ flag)
{
    __shared__ int accs[NN_PER_BLK * ACC_STRIDE];
    int tid = threadIdx.x;
    int b = blockIdx.x;
    int n0 = b * NN_PER_BLK;

    for (int i = tid; i < NN_PER_BLK * ACC_STRIDE; i += 256) accs[i] = 0;
    __syncthreads();

    for (int cc = tid; cc < NCHUNK; cc += 256) {
        const int* dp = dir + (size_t)cc * DIRW + b;
        int d0 = dp[0], d1 = dp[1];
        const int* run = runs + (size_t)cc * RUNW;
        for (int k = d0; k < d1; ++k) {
            int4 a  = *(const int4*)(run + (size_t)k * 8);
            int4 bb = *(const int4*)(run + (size_t)k * 8 + 4);
            unsigned m = (unsigned)a.x;
            int* acc = &accs[bb.z * ACC_STRIDE];
            while (m) {
                int t = __ffs(m) - 1;
                m &= m - 1;
                atomicAdd(&acc[t * 5 + 0], a.y);
                atomicAdd(&acc[t * 5 + 1], a.z);
                atomicAdd(&acc[t * 5 + 2], a.w);
                atomicAdd(&acc[t * 5 + 3], bb.x);
                atomicAdd(&acc[t * 5 + 4], bb.y);
            }
        }
    }
    __syncthreads();

    if (tid >= NN_PER_BLK) return;
    int n = n0 + tid;
    if (n >= N_NEURONS) return;
    const int* acc = &accs[tid * ACC_STRIDE];

    float dec = decay[n], cfa = cf[n], vr = vres[n], tr = tref[n];
    float ek0 = expf(-DT * kk[2 * n]), ek1 = expf(-DT * kk[2 * n + 1]);
    float aa0 = aamps[2 * n], aa1 = aamps[2 * n + 1];
    float vt = vth[n], nm = norm[n], g = gg[n];
    float sd0 = sdec[0], sd1 = sdec[1], sd2 = sdec[2], sd3 = sdec[3], sd4 = sdec[4];
    float pi0 = psci[0], pi1 = psci[1], pi2 = psci[2], pi3 = psci[3], pi4 = psci[4];

    float pr0 = 0.f, pr1 = 0.f, pr2 = 0.f, pr3 = 0.f, pr4 = 0.f;
    float pc0 = 0.f, pc1 = 0.f, pc2 = 0.f, pc3 = 0.f, pc4 = 0.f;
    float v = 0.f, r = 0.f, a0 = 0.f, a1 = 0.f, pz = 0.f;
    bool anyf = false;

#pragma unroll
    for (int t = 0; t < T_STEPS; ++t) {
        float ic = pc0 + pc1 + pc2 + pc3 + pc4;      // input_current uses OLD psc
        float c1 = ic + a0 + a1 + g;
        float dv = dec * v + cfa * c1;
        float nv = (pz > 0.5f) ? vr : dv;
        float nr = r + pz * tr - DT;
        nr = fminf(fmaxf(nr, 0.0f), tr);
        a0 = ek0 * a0 + pz * aa0;
        a1 = ek1 * a1 + pz * aa1;

        float i0 = (float)((double)acc[t * 5 + 0] * INV_SCALE);
        float i1 = (float)((double)acc[t * 5 + 1] * INV_SCALE);
        float i2 = (float)((double)acc[t * 5 + 2] * INV_SCALE);
        float i3 = (float)((double)acc[t * 5 + 3] * INV_SCALE);
        float i4 = (float)((double)acc[t * 5 + 4] * INV_SCALE);

        float np0 = pc0 * sd0 + DT * sd0 * pr0;      // new psc from OLD psc_rise
        float np1 = pc1 * sd1 + DT * sd1 * pr1;
        float np2 = pc2 * sd2 + DT * sd2 * pr2;
        float np3 = pc3 * sd3 + DT * sd3 * pr3;
        float np4 = pc4 * sd4 + DT * sd4 * pr4;
        pr0 = pr0 * sd0 + i0 * pi0;  pc0 = np0;
        pr1 = pr1 * sd1 + i1 * pi1;  pc1 = np1;
        pr2 = pr2 * sd2 + i2 * pi2;  pc2 = np2;
        pr3 = pr3 * sd3 + i3 * pi3;  pc3 = np3;
        pr4 = pr4 * sd4 + i4 * pi4;  pc4 = np4;

        v = nv; r = nr;
        float vsc = (nv - vt) / nm;
        float z = (vsc > 0.0f) ? 1.0f : 0.0f;
        float nz = (nr > 0.0f) ? 0.0f : z;
        out[(size_t)t * N_NEURONS + n] = nz;
        pz = nz;
        anyf = anyf || (nz != 0.0f);
    }
    if (anyf) atomicAdd(flag, 1);
}

// Exact coupled redo inside ONE workgroup; early-exits if no spike detected.
__global__ void __launch_bounds__(1024) fallback_redo(
    const int* __restrict__ dir, const int* __restrict__ runs,
    const int* __restrict__ rec_idx, const float* __restrict__ rec_w,
    const float* __restrict__ rec_fac,
    const float* __restrict__ decay, const float* __restrict__ cf,
    const float* __restrict__ vres, const float* __restrict__ tref,
    const float* __restrict__ kk, const float* __restrict__ aamps,
    const float* __restrict__ vth, const float* __restrict__ norm,
    const float* __restrict__ gg, const float* __restrict__ sdec,
    const float* __restrict__ psci,
    float* __restrict__ zbuf, float* __restrict__ vv, float* __restrict__ rr,
    float* __restrict__ asc, float* __restrict__ pra, float* __restrict__ pca,
    int* __restrict__ inpi, float* __restrict__ out, const int* __restrict__ flag)
{
    if (flag[0] == 0) return;
    int tid = threadIdx.x;
    for (int i = tid; i < N_NEURONS; i += 1024) { vv[i] = 0.f; rr[i] = 0.f; }
    for (int i = tid; i < 2 * N_NEURONS; i += 1024) asc[i] = 0.f;
    for (int i = tid; i < NSYN * N_NEURONS; i += 1024) { pra[i] = 0.f; pca[i] = 0.f; }
    for (int i = tid; i < MAX_DELAY * N_NEURONS; i += 1024) zbuf[i] = 0.f;
    __syncthreads();

    for (int t = 0; t < T_STEPS; ++t) {
        for (int i = tid; i < NSYN * N_NEURONS; i += 1024) inpi[i] = 0;
        __syncthreads();
        // external input for step t: threads walk chunks via the directory
        // (device atomics within the single block; int sums order-invariant)
        for (int cc = tid; cc < NCHUNK; cc += 1024) {
            const int* dp  = dir + (size_t)cc * DIRW;
            const int* run = runs + (size_t)cc * RUNW;
            for (int b2 = 0; b2 < NTGT; ++b2) {
                int d0 = dp[b2], d1 = dp[b2 + 1];
                for (int k = d0; k < d1; ++k) {
                    int4 a  = *(const int4*)(run + (size_t)k * 8);
                    int4 bb = *(const int4*)(run + (size_t)k * 8 + 4);
                    if (((unsigned)a.x >> t) & 1u) {
                        int post = b2 * NN_PER_BLK + bb.z;
                        atomicAdd(&inpi[post * NSYN + 0], a.y);
                        atomicAdd(&inpi[post * NSYN + 1], a.z);
                        atomicAdd(&inpi[post * NSYN + 2], a.w);
                        atomicAdd(&inpi[post * NSYN + 3], bb.x);
                        atomicAdd(&inpi[post * NSYN + 4], bb.y);
                    }
                }
            }
        }
        __syncthreads();
        if (t > 0) {
            for (int e = tid; e < E_REC; e += 1024) {
                int2 pcol = ((const int2*)rec_idx)[e];
                int post = pcol.x, col = pcol.y;
                int d1 = col / N_NEURONS;
                int pre = col - d1 * N_NEURONS;
                int st = t - 1 - d1;
                if (st < 0) continue;
                if (zbuf[(st % MAX_DELAY) * N_NEURONS + pre] != 0.0f) {
                    float w = rec_w[e];
                    atomicAdd(&inpi[post * NSYN + 0], __float2int_rn(w * rec_fac[5 * e + 0] * SCALE_F));
                    atomicAdd(&inpi[post * NSYN + 1], __float2int_rn(w * rec_fac[5 * e + 1] * SCALE_F));
                    atomicAdd(&inpi[post * NSYN + 2], __float2int_rn(w * rec_fac[5 * e + 2] * SCALE_F));
                    atomicAdd(&inpi[post * NSYN + 3], __float2int_rn(w * rec_fac[5 * e + 3] * SCALE_F));
                    atomicAdd(&inpi[post * NSYN + 4], __float2int_rn(w * rec_fac[5 * e + 4] * SCALE_F));
                }
            }
        }
        __syncthreads();
        for (int n = tid; n < N_NEURONS; n += 1024) {
            float pz = (t == 0) ? 0.f : zbuf[((t - 1) % MAX_DELAY) * N_NEURONS + n];
            float prx[NSYN], pcx[NSYN];
            float ic = 0.f;
#pragma unroll
            for (int s = 0; s < NSYN; ++s) {
                prx[s] = pra[n * NSYN + s];
                pcx[s] = pca[n * NSYN + s];
                ic += pcx[s];
            }
            float a0 = asc[2 * n], a1 = asc[2 * n + 1];
            float c1 = ic + a0 + a1 + gg[n];
            float dv = decay[n] * vv[n] + cf[n] * c1;
            float nv = (pz > 0.5f) ? vres[n] : dv;
            float tr = tref[n];
            float nr = rr[n] + pz * tr - DT;
            nr = fminf(fmaxf(nr, 0.0f), tr);
            asc[2 * n]     = expf(-DT * kk[2 * n])     * a0 + pz * aamps[2 * n];
            asc[2 * n + 1] = expf(-DT * kk[2 * n + 1]) * a1 + pz * aamps[2 * n + 1];
#pragma unroll
            for (int s = 0; s < NSYN; ++s) {
                float is = (float)((double)inpi[n * NSYN + s] * INV_SCALE);
                float sd = sdec[s];
                float np = pcx[s] * sd + DT * sd * prx[s];
                pra[n * NSYN + s] = prx[s] * sd + is * psci[s];
                pca[n * NSYN + s] = np;
            }
            vv[n] = nv; rr[n] = nr;
            float vsc = (nv - vth[n]) / norm[n];
            float z = (vsc > 0.0f) ? 1.0f : 0.0f;
            float nz = (nr > 0.0f) ? 0.0f : z;
            zbuf[(t % MAX_DELAY) * N_NEURONS + n] = nz;
            out[(size_t)t * N_NEURONS + n] = nz;
        }
        __syncthreads();
    }
}

extern "C" void kernel_launch(void* const* d_in, const int* in_sizes, int n_in,
                              void* d_out, int out_size, void* d_ws, size_t ws_size,
                              hipStream_t stream) {
    const float* lgn_spikes  = (const float*)d_in[0];
    const float* bkg_spikes  = (const float*)d_in[1];
    const int*   rec_indices = (const int*)  d_in[2];
    const float* rec_w       = (const float*)d_in[3];
    const float* rec_factors = (const float*)d_in[4];
    const int*   lgn_indices = (const int*)  d_in[5];
    const float* lgn_w       = (const float*)d_in[6];
    const float* lgn_factors = (const float*)d_in[7];
    const int*   bkg_indices = (const int*)  d_in[8];
    const float* bkg_w       = (const float*)d_in[9];
    const float* bkg_factors = (const float*)d_in[10];
    const float* decay       = (const float*)d_in[11];
    const float* current_factor = (const float*)d_in[12];
    const float* v_reset     = (const float*)d_in[13];
    const float* t_ref       = (const float*)d_in[14];
    const float* k           = (const float*)d_in[15];
    const float* asc_amps    = (const float*)d_in[16];
    const float* v_th        = (const float*)d_in[17];
    const float* normalizer  = (const float*)d_in[18];
    const float* gathered_g  = (const float*)d_in[19];
    const float* syn_decay   = (const float*)d_in[20];
    const float* psc_initial = (const float*)d_in[21];

    float* ws = (float*)d_ws;
    int*      flag = (int*)(ws + OFF_FLAG);
    unsigned* bits = (unsigned*)(ws + OFF_BITS);
    int*      dir  = (int*)(ws + OFF_DIR);
    int*      runs = (int*)(ws + OFF_RUNS);
    float*    zbuf = ws + OFF_ZBUF;
    float*    vv   = ws + OFF_V;
    float*    rr   = ws + OFF_R;
    float*    asc  = ws + OFF_ASC;
    float*    pra  = ws + OFF_PR;
    float*    pca  = ws + OFF_PC;
    int*      inpi = (int*)(ws + OFF_INPI);
    float*    out  = (float*)d_out;

    prep<<<(32 + N_SRC + 255) / 256, 256, 0, stream>>>(lgn_spikes, bkg_spikes, bits, flag);
    sort_pack<<<NCHUNK, 1024, 0, stream>>>(
        lgn_indices, lgn_w, lgn_factors, bkg_indices, bkg_w, bkg_factors,
        bits, dir, runs);
    fused_scan<<<NTGT, 256, 0, stream>>>(
        dir, runs,
        decay, current_factor, v_reset, t_ref, k, asc_amps,
        v_th, normalizer, gathered_g, syn_decay, psc_initial,
        out, flag);
    fallback_redo<<<1, 1024, 0, stream>>>(
        dir, runs, rec_indices, rec_w, rec_factors,
        decay, current_factor, v_reset, t_ref, k, asc_amps,
        v_th, normalizer, gathered_g, syn_decay, psc_initial,
        zbuf, vv, rr, asc, pra, pca, inpi, out, flag);
}

// Round 12
// 51.183 us; speedup vs baseline: 1.1691x; 1.0798x over previous
//
#include <hip/hip_runtime.h>

#define N_NEURONS 100000
#define MAX_DELAY 5
#define NSYN 5
#define T_STEPS 20
#define N_LGN 17400
#define N_BKG 100
#define N_SRC (N_LGN + N_BKG)        // 17500
#define E_REC 2000000
#define E_LGN 600000
#define E_BKG 200000
#define E_EXT (E_LGN + E_BKG)        // 800000
#define DT 1.0f
#define NN_PER_BLK 64
#define NTGT 1563                    // consumer blocks = ceil(N/64)
#define DIRW (NTGT + 1)              // 1564
#define NCHUNK 512                   // producer chunks (2 blocks/CU)
#define CHUNK 1563                   // 512*1563 = 800,256 >= E_EXT
#define RUNW (CHUNK * 8)             // ints per chunk run region
#define ACC_STRIDE 101               // 100 + 1 pad
#define SCALE_F 16777216.0f          // 2^24 fixed-point (order-invariant accumulation)
#define INV_SCALE (1.0 / 16777216.0)

// ---------------- ws layout (4-byte units) ----------------
#define OFF_FLAG   0u                // int[32]: [0]=any-spike flag
#define OFF_BITS   32u               // uint[N_SRC]
#define OFF_DIR    17536u            // int[NCHUNK][DIRW] = 800,768
#define OFF_RUNS   818304u           // int[NCHUNK][CHUNK][8] = 6,402,048
#define OFF_ZBUF   7220352u          // float[5N]  (fallback only)
#define OFF_V      7720352u
#define OFF_R      7820352u
#define OFF_ASC    7920352u          // float[2N]
#define OFF_PR     8120352u          // float[5N]
#define OFF_PC     8620352u          // float[5N]
#define OFF_INPI   9120352u          // int[5N]
// ends 9,620,352 units = 38.5 MB

// Zero flag + build 20-bit spike masks.
__global__ void prep(const float* __restrict__ lgn, const float* __restrict__ bkg,
                     unsigned* __restrict__ bits, int* __restrict__ zp) {
    int tid = blockIdx.x * blockDim.x + threadIdx.x;
    if (tid < 32) zp[tid] = 0;
    int i = tid - 32;
    if (i < 0 || i >= N_SRC) return;
    unsigned b = 0;
    if (i < N_LGN) {
#pragma unroll
        for (int t = 0; t < T_STEPS; ++t)
            if (lgn[t * N_LGN + i] != 0.0f) b |= (1u << t);
    } else {
        int j = i - N_LGN;
#pragma unroll
        for (int t = 0; t < T_STEPS; ++t)
            if (bkg[t * N_BKG + j] != 0.0f) b |= (1u << t);
    }
    bits[i] = b;
}

// Single-pass counting-sort pack. Each thread loads its <=2 edges ONCE into
// registers (latency hides under LDS zero + scan), histograms from registers,
// wave-shuffle scan (3 barriers total), writes records from registers.
// Zero global atomics. Slot order within a (chunk,target) group varies across
// replays (LDS cursor) but consumer int accumulation is order-invariant.
__global__ void __launch_bounds__(1024) sort_pack(
    const int* __restrict__ lgn_idx, const float* __restrict__ lgn_w,
    const float* __restrict__ lgn_fac,
    const int* __restrict__ bkg_idx, const float* __restrict__ bkg_w,
    const float* __restrict__ bkg_fac,
    const unsigned* __restrict__ bits,
    int* __restrict__ dir, int* __restrict__ runs)
{
    __shared__ int hist[NTGT];
    __shared__ int cur[NTGT];
    __shared__ int wsum[16];
    int tid = threadIdx.x, c = blockIdx.x;
    int e0 = c * CHUNK;
    int e1 = e0 + CHUNK; if (e1 > E_EXT) e1 = E_EXT;

    for (int i = tid; i < NTGT; i += 1024) hist[i] = 0;

    // Load edge 0 (e0+tid) and edge 1 (e0+tid+1024) into registers.
    unsigned m0 = 0, m1 = 0;
    int p0 = 0, p1 = 0;
    int qa0 = 0, qb0 = 0, qc0 = 0, qd0 = 0, qe0 = 0;
    int qa1 = 0, qb1 = 0, qc1 = 0, qd1 = 0, qe1 = 0;
    {
        int e = e0 + tid;
        if (e < e1) {
            int post, srow;
            if (e < E_LGN) { int2 p = ((const int2*)lgn_idx)[e]; post = p.x; srow = p.y; }
            else           { int2 p = ((const int2*)bkg_idx)[e - E_LGN]; post = p.x; srow = N_LGN + p.y; }
            unsigned m = bits[srow];
            if (m) {
                float w; const float* f;
                if (e < E_LGN) { w = lgn_w[e]; f = lgn_fac + 5 * (size_t)e; }
                else { int b = e - E_LGN; w = bkg_w[b]; f = bkg_fac + 5 * (size_t)b; }
                float wsc = w * SCALE_F;
                qa0 = __float2int_rn(wsc * f[0]);
                qb0 = __float2int_rn(wsc * f[1]);
                qc0 = __float2int_rn(wsc * f[2]);
                qd0 = __float2int_rn(wsc * f[3]);
                qe0 = __float2int_rn(wsc * f[4]);
                m0 = m; p0 = post;
            }
        }
    }
    {
        int e = e0 + tid + 1024;
        if (e < e1) {
            int post, srow;
            if (e < E_LGN) { int2 p = ((const int2*)lgn_idx)[e]; post = p.x; srow = p.y; }
            else           { int2 p = ((const int2*)bkg_idx)[e - E_LGN]; post = p.x; srow = N_LGN + p.y; }
            unsigned m = bits[srow];
            if (m) {
                float w; const float* f;
                if (e < E_LGN) { w = lgn_w[e]; f = lgn_fac + 5 * (size_t)e; }
                else { int b = e - E_LGN; w = bkg_w[b]; f = bkg_fac + 5 * (size_t)b; }
                float wsc = w * SCALE_F;
                qa1 = __float2int_rn(wsc * f[0]);
                qb1 = __float2int_rn(wsc * f[1]);
                qc1 = __float2int_rn(wsc * f[2]);
                qd1 = __float2int_rn(wsc * f[3]);
                qe1 = __float2int_rn(wsc * f[4]);
                m1 = m; p1 = post;
            }
        }
    }
    __syncthreads();

    if (m0) atomicAdd(&hist[p0 >> 6], 1);
    if (m1) atomicAdd(&hist[p1 >> 6], 1);
    __syncthreads();

    // Exclusive scan over 1563 entries: 2/thread + wave-shuffle scan.
    int base = tid * 2;
    int v0 = (base < NTGT) ? hist[base] : 0;
    int v1 = (base + 1 < NTGT) ? hist[base + 1] : 0;
    int s = v0 + v1;
    int lane = tid & 63, wid = tid >> 6;
    int inc = s;
#pragma unroll
    for (int off = 1; off < 64; off <<= 1) {
        int v = __shfl_up(inc, off);
        if (lane >= off) inc += v;
    }
    if (lane == 63) wsum[wid] = inc;
    __syncthreads();
    if (tid < 16) {
        int v = wsum[tid];
        int i2 = v;
#pragma unroll
        for (int off = 1; off < 16; off <<= 1) {
            int u = __shfl_up(i2, off);
            if (tid >= off) i2 += u;
        }
        wsum[tid] = i2 - v;   // exclusive wave offset
    }
    __syncthreads();
    int excl = wsum[wid] + (inc - s);
    if (base < NTGT) {
        cur[base] = excl;
        dir[(size_t)c * DIRW + base] = excl;
    }
    if (base + 1 <= NTGT) {
        if (base + 1 < NTGT) cur[base + 1] = excl + v0;
        dir[(size_t)c * DIRW + base + 1] = excl + v0;   // base+1==NTGT -> total
    }
    __syncthreads();

    // Write records from registers into the chunk's private dense region.
    int* run = runs + (size_t)c * RUNW;
    if (m0) {
        int slot = atomicAdd(&cur[p0 >> 6], 1);         // LDS atomic
        int4* d = (int4*)(run + (size_t)slot * 8);
        d[0] = make_int4((int)m0, qa0, qb0, qc0);
        d[1] = make_int4(qd0, qe0, p0 & 63, 0);
    }
    if (m1) {
        int slot = atomicAdd(&cur[p1 >> 6], 1);
        int4* d = (int4*)(run + (size_t)slot * 8);
        d[0] = make_int4((int)m1, qa1, qb1, qc1);
        d[1] = make_int4(qd1, qe1, p1 & 63, 0);
    }
}

// Consumer: thread t streams chunks {t, t+256} for this block (dir-indexed,
// pure loads), LDS-atomics into acc[post_local]; then 64 threads run the
// 20-step GLIF scan (numerics identical to round 11's passing kernel).
__global__ void __launch_bounds__(256) fused_scan(
    const int* __restrict__ dir, const int* __restrict__ runs,
    const float* __restrict__ decay, const float* __restrict__ cf,
    const float* __restrict__ vres, const float* __restrict__ tref,
    const float* __restrict__ kk, const float* __restrict__ aamps,
    const float* __restrict__ vth, const float* __restrict__ norm,
    const float* __restrict__ gg, const float* __restrict__ sdec,
    const float* __restrict__ psci,
    float* __restrict__ out, int* __restrict__ flag)
{
    __shared__ int accs[NN_PER_BLK * ACC_STRIDE];
    int tid = threadIdx.x;
    int b = blockIdx.x;
    int n0 = b * NN_PER_BLK;

    for (int i = tid; i < NN_PER_BLK * ACC_STRIDE; i += 256) accs[i] = 0;
    __syncthreads();

    for (int cc = tid; cc < NCHUNK; cc += 256) {
        const int* dp = dir + (size_t)cc * DIRW + b;
        int d0 = dp[0], d1 = dp[1];
        const int* run = runs + (size_t)cc * RUNW;
        for (int k = d0; k < d1; ++k) {
            int4 a  = *(const int4*)(run + (size_t)k * 8);
            int4 bb = *(const int4*)(run + (size_t)k * 8 + 4);
            unsigned m = (unsigned)a.x;
            int* acc = &accs[bb.z * ACC_STRIDE];
            while (m) {
                int t = __ffs(m) - 1;
                m &= m - 1;
                atomicAdd(&acc[t * 5 + 0], a.y);
                atomicAdd(&acc[t * 5 + 1], a.z);
                atomicAdd(&acc[t * 5 + 2], a.w);
                atomicAdd(&acc[t * 5 + 3], bb.x);
                atomicAdd(&acc[t * 5 + 4], bb.y);
            }
        }
    }
    __syncthreads();

    if (tid >= NN_PER_BLK) return;
    int n = n0 + tid;
    if (n >= N_NEURONS) return;
    const int* acc = &accs[tid * ACC_STRIDE];

    float dec = decay[n], cfa = cf[n], vr = vres[n], tr = tref[n];
    float ek0 = expf(-DT * kk[2 * n]), ek1 = expf(-DT * kk[2 * n + 1]);
    float aa0 = aamps[2 * n], aa1 = aamps[2 * n + 1];
    float vt = vth[n], nm = norm[n], g = gg[n];
    float sd0 = sdec[0], sd1 = sdec[1], sd2 = sdec[2], sd3 = sdec[3], sd4 = sdec[4];
    float pi0 = psci[0], pi1 = psci[1], pi2 = psci[2], pi3 = psci[3], pi4 = psci[4];

    float pr0 = 0.f, pr1 = 0.f, pr2 = 0.f, pr3 = 0.f, pr4 = 0.f;
    float pc0 = 0.f, pc1 = 0.f, pc2 = 0.f, pc3 = 0.f, pc4 = 0.f;
    float v = 0.f, r = 0.f, a0 = 0.f, a1 = 0.f, pz = 0.f;
    bool anyf = false;

#pragma unroll
    for (int t = 0; t < T_STEPS; ++t) {
        float ic = pc0 + pc1 + pc2 + pc3 + pc4;      // input_current uses OLD psc
        float c1 = ic + a0 + a1 + g;
        float dv = dec * v + cfa * c1;
        float nv = (pz > 0.5f) ? vr : dv;
        float nr = r + pz * tr - DT;
        nr = fminf(fmaxf(nr, 0.0f), tr);
        a0 = ek0 * a0 + pz * aa0;
        a1 = ek1 * a1 + pz * aa1;

        float i0 = (float)((double)acc[t * 5 + 0] * INV_SCALE);
        float i1 = (float)((double)acc[t * 5 + 1] * INV_SCALE);
        float i2 = (float)((double)acc[t * 5 + 2] * INV_SCALE);
        float i3 = (float)((double)acc[t * 5 + 3] * INV_SCALE);
        float i4 = (float)((double)acc[t * 5 + 4] * INV_SCALE);

        float np0 = pc0 * sd0 + DT * sd0 * pr0;      // new psc from OLD psc_rise
        float np1 = pc1 * sd1 + DT * sd1 * pr1;
        float np2 = pc2 * sd2 + DT * sd2 * pr2;
        float np3 = pc3 * sd3 + DT * sd3 * pr3;
        float np4 = pc4 * sd4 + DT * sd4 * pr4;
        pr0 = pr0 * sd0 + i0 * pi0;  pc0 = np0;
        pr1 = pr1 * sd1 + i1 * pi1;  pc1 = np1;
        pr2 = pr2 * sd2 + i2 * pi2;  pc2 = np2;
        pr3 = pr3 * sd3 + i3 * pi3;  pc3 = np3;
        pr4 = pr4 * sd4 + i4 * pi4;  pc4 = np4;

        v = nv; r = nr;
        float vsc = (nv - vt) / nm;
        float z = (vsc > 0.0f) ? 1.0f : 0.0f;
        float nz = (nr > 0.0f) ? 0.0f : z;
        out[(size_t)t * N_NEURONS + n] = nz;
        pz = nz;
        anyf = anyf || (nz != 0.0f);
    }
    if (anyf) atomicAdd(flag, 1);
}

// Exact coupled redo inside ONE workgroup; early-exits if no spike detected.
__global__ void __launch_bounds__(1024) fallback_redo(
    const int* __restrict__ dir, const int* __restrict__ runs,
    const int* __restrict__ rec_idx, const float* __restrict__ rec_w,
    const float* __restrict__ rec_fac,
    const float* __restrict__ decay, const float* __restrict__ cf,
    const float* __restrict__ vres, const float* __restrict__ tref,
    const float* __restrict__ kk, const float* __restrict__ aamps,
    const float* __restrict__ vth, const float* __restrict__ norm,
    const float* __restrict__ gg, const float* __restrict__ sdec,
    const float* __restrict__ psci,
    float* __restrict__ zbuf, float* __restrict__ vv, float* __restrict__ rr,
    float* __restrict__ asc, float* __restrict__ pra, float* __restrict__ pca,
    int* __restrict__ inpi, float* __restrict__ out, const int* __restrict__ flag)
{
    if (flag[0] == 0) return;
    int tid = threadIdx.x;
    for (int i = tid; i < N_NEURONS; i += 1024) { vv[i] = 0.f; rr[i] = 0.f; }
    for (int i = tid; i < 2 * N_NEURONS; i += 1024) asc[i] = 0.f;
    for (int i = tid; i < NSYN * N_NEURONS; i += 1024) { pra[i] = 0.f; pca[i] = 0.f; }
    for (int i = tid; i < MAX_DELAY * N_NEURONS; i += 1024) zbuf[i] = 0.f;
    __syncthreads();

    for (int t = 0; t < T_STEPS; ++t) {
        for (int i = tid; i < NSYN * N_NEURONS; i += 1024) inpi[i] = 0;
        __syncthreads();
        for (int cc = tid; cc < NCHUNK; cc += 1024) {
            const int* dp  = dir + (size_t)cc * DIRW;
            const int* run = runs + (size_t)cc * RUNW;
            for (int b2 = 0; b2 < NTGT; ++b2) {
                int d0 = dp[b2], d1 = dp[b2 + 1];
                for (int k = d0; k < d1; ++k) {
                    int4 a  = *(const int4*)(run + (size_t)k * 8);
                    int4 bb = *(const int4*)(run + (size_t)k * 8 + 4);
                    if (((unsigned)a.x >> t) & 1u) {
                        int post = b2 * NN_PER_BLK + bb.z;
                        atomicAdd(&inpi[post * NSYN + 0], a.y);
                        atomicAdd(&inpi[post * NSYN + 1], a.z);
                        atomicAdd(&inpi[post * NSYN + 2], a.w);
                        atomicAdd(&inpi[post * NSYN + 3], bb.x);
                        atomicAdd(&inpi[post * NSYN + 4], bb.y);
                    }
                }
            }
        }
        __syncthreads();
        if (t > 0) {
            for (int e = tid; e < E_REC; e += 1024) {
                int2 pcol = ((const int2*)rec_idx)[e];
                int post = pcol.x, col = pcol.y;
                int d1 = col / N_NEURONS;
                int pre = col - d1 * N_NEURONS;
                int st = t - 1 - d1;
                if (st < 0) continue;
                if (zbuf[(st % MAX_DELAY) * N_NEURONS + pre] != 0.0f) {
                    float w = rec_w[e];
                    atomicAdd(&inpi[post * NSYN + 0], __float2int_rn(w * rec_fac[5 * e + 0] * SCALE_F));
                    atomicAdd(&inpi[post * NSYN + 1], __float2int_rn(w * rec_fac[5 * e + 1] * SCALE_F));
                    atomicAdd(&inpi[post * NSYN + 2], __float2int_rn(w * rec_fac[5 * e + 2] * SCALE_F));
                    atomicAdd(&inpi[post * NSYN + 3], __float2int_rn(w * rec_fac[5 * e + 3] * SCALE_F));
                    atomicAdd(&inpi[post * NSYN + 4], __float2int_rn(w * rec_fac[5 * e + 4] * SCALE_F));
                }
            }
        }
        __syncthreads();
        for (int n = tid; n < N_NEURONS; n += 1024) {
            float pz = (t == 0) ? 0.f : zbuf[((t - 1) % MAX_DELAY) * N_NEURONS + n];
            float prx[NSYN], pcx[NSYN];
            float ic = 0.f;
#pragma unroll
            for (int s = 0; s < NSYN; ++s) {
                prx[s] = pra[n * NSYN + s];
                pcx[s] = pca[n * NSYN + s];
                ic += pcx[s];
            }
            float a0 = asc[2 * n], a1 = asc[2 * n + 1];
            float c1 = ic + a0 + a1 + gg[n];
            float dv = decay[n] * vv[n] + cf[n] * c1;
            float nv = (pz > 0.5f) ? vres[n] : dv;
            float tr = tref[n];
            float nr = rr[n] + pz * tr - DT;
            nr = fminf(fmaxf(nr, 0.0f), tr);
            asc[2 * n]     = expf(-DT * kk[2 * n])     * a0 + pz * aamps[2 * n];
            asc[2 * n + 1] = expf(-DT * kk[2 * n + 1]) * a1 + pz * aamps[2 * n + 1];
#pragma unroll
            for (int s = 0; s < NSYN; ++s) {
                float is = (float)((double)inpi[n * NSYN + s] * INV_SCALE);
                float sd = sdec[s];
                float np = pcx[s] * sd + DT * sd * prx[s];
                pra[n * NSYN + s] = prx[s] * sd + is * psci[s];
                pca[n * NSYN + s] = np;
            }
            vv[n] = nv; rr[n] = nr;
            float vsc = (nv - vth[n]) / norm[n];
            float z = (vsc > 0.0f) ? 1.0f : 0.0f;
            float nz = (nr > 0.0f) ? 0.0f : z;
            zbuf[(t % MAX_DELAY) * N_NEURONS + n] = nz;
            out[(size_t)t * N_NEURONS + n] = nz;
        }
        __syncthreads();
    }
}

extern "C" void kernel_launch(void* const* d_in, const int* in_sizes, int n_in,
                              void* d_out, int out_size, void* d_ws, size_t ws_size,
                              hipStream_t stream) {
    const float* lgn_spikes  = (const float*)d_in[0];
    const float* bkg_spikes  = (const float*)d_in[1];
    const int*   rec_indices = (const int*)  d_in[2];
    const float* rec_w       = (const float*)d_in[3];
    const float* rec_factors = (const float*)d_in[4];
    const int*   lgn_indices = (const int*)  d_in[5];
    const float* lgn_w       = (const float*)d_in[6];
    const float* lgn_factors = (const float*)d_in[7];
    const int*   bkg_indices = (const int*)  d_in[8];
    const float* bkg_w       = (const float*)d_in[9];
    const float* bkg_factors = (const float*)d_in[10];
    const float* decay       = (const float*)d_in[11];
    const float* current_factor = (const float*)d_in[12];
    const float* v_reset     = (const float*)d_in[13];
    const float* t_ref       = (const float*)d_in[14];
    const float* k           = (const float*)d_in[15];
    const float* asc_amps    = (const float*)d_in[16];
    const float* v_th        = (const float*)d_in[17];
    const float* normalizer  = (const float*)d_in[18];
    const float* gathered_g  = (const float*)d_in[19];
    const float* syn_decay   = (const float*)d_in[20];
    const float* psc_initial = (const float*)d_in[21];

    float* ws = (float*)d_ws;
    int*      flag = (int*)(ws + OFF_FLAG);
    unsigned* bits = (unsigned*)(ws + OFF_BITS);
    int*      dir  = (int*)(ws + OFF_DIR);
    int*      runs = (int*)(ws + OFF_RUNS);
    float*    zbuf = ws + OFF_ZBUF;
    float*    vv   = ws + OFF_V;
    float*    rr   = ws + OFF_R;
    float*    asc  = ws + OFF_ASC;
    float*    pra  = ws + OFF_PR;
    float*    pca  = ws + OFF_PC;
    int*      inpi = (int*)(ws + OFF_INPI);
    float*    out  = (float*)d_out;

    prep<<<(32 + N_SRC + 255) / 256, 256, 0, stream>>>(lgn_spikes, bkg_spikes, bits, flag);
    sort_pack<<<NCHUNK, 1024, 0, stream>>>(
        lgn_indices, lgn_w, lgn_factors, bkg_indices, bkg_w, bkg_factors,
        bits, dir, runs);
    fused_scan<<<NTGT, 256, 0, stream>>>(
        dir, runs,
        decay, current_factor, v_reset, t_ref, k, asc_amps,
        v_th, normalizer, gathered_g, syn_decay, psc_initial,
        out, flag);
    fallback_redo<<<1, 1024, 0, stream>>>(
        dir, runs, rec_indices, rec_w, rec_factors,
        decay, current_factor, v_reset, t_ref, k, asc_amps,
        v_th, normalizer, gathered_g, syn_decay, psc_initial,
        zbuf, vv, rr, asc, pra, pca, inpi, out, flag);
}